// Round 3
// baseline (615.688 us; speedup 1.0000x reference)
//
#include <hip/hip_runtime.h>
#include <hip/hip_bf16.h>

// Problem constants
constexpr int B_   = 32;
constexpr int CIN  = 64;
constexpr int HIN  = 128;
constexpr int WIN  = 128;
constexpr int COUT = 128;
constexpr int HO   = 126;
constexpr int WO   = 126;
constexpr int HP   = 63;
constexpr int WP   = 63;
constexpr int NG   = 8;
constexpr float EPS = 1e-5f;

typedef _Float16 f16x8 __attribute__((ext_vector_type(8)));
typedef _Float16 f16x2 __attribute__((ext_vector_type(2)));
typedef float    f32x4 __attribute__((ext_vector_type(4)));

// ws layout (bytes):
//   stats @ 0        : 512 floats (2 KB, rounded to 4096)
//   Wh    @ 4096     : 9*128*64 f16 = 147456 B          (ends 151552)
//   xh    @ 151552   : 32*128*128*64 f16 = 64 MB        (ends 67260416)
//   yp    @ 67260416 : 32*128*63*64 f16 = 33 MB (padded wp-stride 64)
// total ~100.3 MB (round-2 proved ws >= 130.2 MB)

// ---------- Prep: W (OIHW fp32) -> Wh[kh*kw][cout][cin] f16 ----------
__global__ __launch_bounds__(256)
void whprep_kernel(const float* __restrict__ W, _Float16* __restrict__ Wh)
{
    int i = blockIdx.x * 256 + threadIdx.x;
    if (i >= 9 * COUT * CIN) return;
    int c  = i & 63;
    int co = (i >> 6) & 127;
    int kk = i >> 13;
    Wh[i] = (_Float16)W[((size_t)co * CIN + c) * 9 + kk];
}

// ---------- Prep: x fp32 NCHW -> xh f16 NHWC ----------
// one block per (h, b): reads 64ch x 128w fp32 coalesced, transposes via LDS,
// writes 128px x 64ch f16 coalesced (16B stores).
__global__ __launch_bounds__(256)
void xprep_kernel(const float* __restrict__ x, _Float16* __restrict__ xh)
{
    const int tid = threadIdx.x;
    const int h = blockIdx.x, b = blockIdx.y;
    __shared__ _Float16 s[64][130];   // pad 130 -> phase1 writes conflict-free

    #pragma unroll
    for (int i = 0; i < 16; ++i) {
        const int flat = i * 256 + tid;          // 0..4095
        const int c  = flat >> 6;                // 0..63
        const int w2 = flat & 63;                // pair index
        const float2 v = *(const float2*)(x + ((size_t)(b * CIN + c) * HIN + h) * WIN + 2 * w2);
        *(f16x2*)(&s[c][2 * w2]) = (f16x2){(_Float16)v.x, (_Float16)v.y};
    }
    __syncthreads();
    #pragma unroll
    for (int i = 0; i < 4; ++i) {
        const int u = i * 256 + tid;             // 0..1023 f16x8 units
        const int w  = u >> 3;                   // 0..127
        const int c0 = (u & 7) * 8;
        f16x8 o;
        #pragma unroll
        for (int j = 0; j < 8; ++j) o[j] = s[c0 + j][w];
        *(f16x8*)(xh + ((size_t)(b * 128 + h) * 128 + w) * 64 + c0) = o;
    }
}

// ---------- Conv (implicit GEMM, MFMA f16, LDS-free) + bias + stats + fused 2x2 pool ----------
// grid (63 row-pairs, 2 w-halves, 32 batch); block 256 = 4 waves, wave w -> couts w*32..+32.
// Wave tile: M = 2 rows x 64 px (mt 0..3 row0, 4..7 row1), N = 32 (nt 0..1), K = 576.
__global__ __launch_bounds__(256, 3)
void conv_mfma_kernel(const _Float16* __restrict__ xh, const _Float16* __restrict__ Wh,
                      const float* __restrict__ bias, const float* __restrict__ gamma,
                      const float* __restrict__ scale,
                      _Float16* __restrict__ yp, float* __restrict__ stats)
{
    const int tid  = threadIdx.x;
    const int lane = tid & 63;
    const int wave = tid >> 6;
    const int ln   = lane & 15;      // n-lane (cout) for B/D, m-lane (pixel) for A
    const int jq   = lane >> 4;      // k-quad
    const int rp   = blockIdx.x;     // row pair 0..62
    const int half = blockIdx.y;     // w-half 0..1
    const int b    = blockIdx.z;
    const int cobase = wave * 32;

    f32x4 acc[8][2];
    #pragma unroll
    for (int mt = 0; mt < 8; ++mt)
        #pragma unroll
        for (int nt = 0; nt < 2; ++nt)
            acc[mt][nt] = (f32x4){0.f, 0.f, 0.f, 0.f};

    // element offset of input row 2*rp of batch b in xh
    const size_t xbase = ((size_t)(b * 128 + 2 * rp)) * 128 * 64;
    const int lanecin = jq * 8;      // cin offset within chunk

    #pragma unroll
    for (int chunk = 0; chunk < 2; ++chunk) {
        #pragma unroll
        for (int kk = 0; kk < 9; ++kk) {
            const int kh = kk / 3, kw = kk % 3;
            const f16x8 B0 = *(const f16x8*)(Wh + kk * 8192 + (cobase + ln) * 64      + chunk * 32 + lanecin);
            const f16x8 B1 = *(const f16x8*)(Wh + kk * 8192 + (cobase + 16 + ln) * 64 + chunk * 32 + lanecin);
            #pragma unroll
            for (int mt = 0; mt < 8; ++mt) {
                const int mrow = mt >> 2;      // 0: out row 2rp, 1: out row 2rp+1
                const int mt4  = mt & 3;
                const f16x8 A = *(const f16x8*)(xh + xbase
                    + ((size_t)(mrow + kh) * 128 + half * 64 + mt4 * 16 + ln + kw) * 64
                    + chunk * 32 + lanecin);
                acc[mt][0] = __builtin_amdgcn_mfma_f32_16x16x32_f16(A, B0, acc[mt][0], 0, 0, 0);
                acc[mt][1] = __builtin_amdgcn_mfma_f32_16x16x32_f16(A, B1, acc[mt][1], 0, 0, 0);
            }
        }
    }

    // ---- epilogue: bias, stats, fused 2x2 max/min-pool, f16 store ----
    float s1[2] = {0.f, 0.f}, s2[2] = {0.f, 0.f};
    #pragma unroll
    for (int nt = 0; nt < 2; ++nt) {
        const int co = cobase + nt * 16 + ln;
        const float bv = bias[co];
        const bool useMin = (gamma[co] * scale[co]) < 0.0f;  // sign of affine slope (rstd > 0)
        const size_t pbase = ((size_t)(b * COUT + co) * HP + rp) * 64;  // padded wp-stride 64
        #pragma unroll
        for (int mt4 = 0; mt4 < 4; ++mt4) {
            const f32x4 v0 = acc[mt4][nt];       // row 2rp,   wo = half*64+mt4*16+jq*4+r
            const f32x4 v1 = acc[mt4 + 4][nt];   // row 2rp+1
            const float a0 = v0.x + bv, a1 = v0.y + bv, a2 = v0.z + bv, a3 = v0.w + bv;
            const float b0 = v1.x + bv, b1 = v1.y + bv, b2 = v1.z + bv, b3 = v1.w + bv;
            const bool lastpair = (half == 1) && (mt4 == 3) && (jq == 3);  // wo 126,127 invalid
            s1[nt] += a0 + a1 + b0 + b1;
            s2[nt] += a0 * a0 + a1 * a1 + b0 * b0 + b1 * b1;
            if (!lastpair) {
                s1[nt] += a2 + a3 + b2 + b3;
                s2[nt] += a2 * a2 + a3 * a3 + b2 * b2 + b3 * b3;
            }
            const float M0 = fmaxf(fmaxf(a0, a1), fmaxf(b0, b1));
            const float m0 = fminf(fminf(a0, a1), fminf(b0, b1));
            const float M1 = fmaxf(fmaxf(a2, a3), fmaxf(b2, b3));
            const float m1 = fminf(fminf(a2, a3), fminf(b2, b3));
            const float p0 = useMin ? m0 : M0;
            const float p1 = useMin ? m1 : M1;
            const int wp0 = half * 32 + mt4 * 8 + jq * 2;
            if (!lastpair)
                *(f16x2*)(yp + pbase + wp0) = (f16x2){(_Float16)p0, (_Float16)p1};
            else
                yp[pbase + wp0] = (_Float16)p0;   // wp 63 doesn't exist
        }
        float r1 = s1[nt], r2 = s2[nt];
        #pragma unroll
        for (int off = 32; off > 0; off >>= 1) {
            r1 += __shfl_down(r1, off);
            r2 += __shfl_down(r2, off);
        }
        if (lane == 0) {
            const int g = wave * 2 + nt;
            atomicAdd(&stats[((size_t)b * NG + g) * 2 + 0], r1);
            atomicAdd(&stats[((size_t)b * NG + g) * 2 + 1], r2);
        }
    }
}

// ---------- GroupNorm affine + clamp on pre-pooled extrema ----------
__global__ __launch_bounds__(256)
void gn_pool_kernel(const _Float16* __restrict__ yp, const float* __restrict__ stats,
                    const float* __restrict__ gamma, const float* __restrict__ beta,
                    const float* __restrict__ scale, float* __restrict__ out)
{
    const int idx = blockIdx.x * 256 + threadIdx.x;
    if (idx >= B_ * COUT * HP * WP) return;
    const int wp = idx % WP;
    const int hp = (idx / WP) % HP;
    const int c  = (idx / (WP * HP)) % COUT;
    const int b  = idx / (WP * HP * COUT);
    const int g  = c >> 4;

    const float s1 = stats[((size_t)b * NG + g) * 2 + 0];
    const float s2 = stats[((size_t)b * NG + g) * 2 + 1];
    constexpr float inv = 1.0f / (float)((COUT / NG) * HO * WO);
    const float mean = s1 * inv;
    const float var  = fmaf(-mean, mean, s2 * inv);
    const float rstd = rsqrtf(var + EPS);
    const float sc   = scale[c];
    const float a    = rstd * gamma[c] * sc;
    const float bb   = fmaf(-mean, rstd * gamma[c], beta[c]) * sc;

    const float v = (float)yp[((size_t)(b * COUT + c) * HP + hp) * 64 + wp];
    float m = fmaf(v, a, bb);      // == pooled(clamp-free affine); extremum matches sign(a)
    m = fminf(fmaxf(m, 0.0f), 1.0f);
    out[idx] = m;
}

extern "C" void kernel_launch(void* const* d_in, const int* in_sizes, int n_in,
                              void* d_out, int out_size, void* d_ws, size_t ws_size,
                              hipStream_t stream)
{
    const float* x     = (const float*)d_in[0];
    const float* W     = (const float*)d_in[1];
    const float* bias  = (const float*)d_in[2];
    const float* scale = (const float*)d_in[3];
    const float* gamma = (const float*)d_in[4];
    const float* beta  = (const float*)d_in[5];

    float*    stats = (float*)d_ws;
    _Float16* Wh    = (_Float16*)((char*)d_ws + 4096);
    _Float16* xh    = (_Float16*)((char*)d_ws + 151552);
    _Float16* yp    = (_Float16*)((char*)d_ws + 67260416);
    float*    out   = (float*)d_out;

    hipMemsetAsync(stats, 0, B_ * NG * 2 * sizeof(float), stream);

    whprep_kernel<<<(9 * COUT * CIN + 255) / 256, 256, 0, stream>>>(W, Wh);
    xprep_kernel<<<dim3(HIN, B_), 256, 0, stream>>>(x, xh);
    conv_mfma_kernel<<<dim3(63, 2, B_), 256, 0, stream>>>(xh, Wh, bias, gamma, scale, yp, stats);

    const int total = B_ * COUT * HP * WP;
    gn_pool_kernel<<<(total + 255) / 256, 256, 0, stream>>>(yp, stats, gamma, beta, scale, out);
}

// Round 4
// 507.186 us; speedup vs baseline: 1.2139x; 1.2139x over previous
//
#include <hip/hip_runtime.h>
#include <hip/hip_bf16.h>

// Problem constants
constexpr int B_   = 32;
constexpr int CIN  = 64;
constexpr int HIN  = 128;
constexpr int WIN  = 128;
constexpr int COUT = 128;
constexpr int HO   = 126;
constexpr int WO   = 126;
constexpr int HP   = 63;
constexpr int WP   = 63;
constexpr int NG   = 8;
constexpr float EPS = 1e-5f;

typedef _Float16 f16x8 __attribute__((ext_vector_type(8)));
typedef _Float16 f16x2 __attribute__((ext_vector_type(2)));
typedef float    f32x16 __attribute__((ext_vector_type(16)));

// ws layout (bytes):
//   stats @ 0        : 512 floats (pad to 4096)
//   Wh    @ 4096     : 9*128*64 f16 = 147456            (ends 151552)
//   xh    @ 151552   : 32*128*128*64 f16 = 64 MB        (ends 67260416; +4KB slack for halo over-read)
//   yp    @ 67264512 : 32*128*63*64 f16 = 33 MB (padded wp-stride 64)

// ---------- Prep: W (OIHW fp32) -> Wh[kh*kw][cout][cin] f16 ----------
__global__ __launch_bounds__(256)
void whprep_kernel(const float* __restrict__ W, _Float16* __restrict__ Wh)
{
    int i = blockIdx.x * 256 + threadIdx.x;
    if (i >= 9 * COUT * CIN) return;
    int c  = i & 63;
    int co = (i >> 6) & 127;
    int kk = i >> 13;
    Wh[i] = (_Float16)W[((size_t)co * CIN + c) * 9 + kk];
}

// ---------- Prep: x fp32 NCHW -> xh f16 NHWC (LDS-free, coalesced) ----------
// grid (64, 32): block handles 2 h-rows; lane spans w -> 256B coalesced reads per c.
__global__ __launch_bounds__(256)
void xprep_kernel(const float* __restrict__ x, _Float16* __restrict__ xh)
{
    const int tid = threadIdx.x;
    const int w = tid & 127;
    const int h = blockIdx.x * 2 + (tid >> 7);
    const int b = blockIdx.y;
    const float* xp = x + ((size_t)b * CIN * HIN + h) * WIN + w;   // + c*16384
    _Float16* op = xh + ((size_t)(b * 128 + h) * 128 + w) * 64;
    #pragma unroll
    for (int cg = 0; cg < 8; ++cg) {
        f16x8 o;
        #pragma unroll
        for (int j = 0; j < 8; ++j)
            o[j] = (_Float16)xp[(size_t)(cg * 8 + j) * (HIN * WIN)];
        *(f16x8*)(op + cg * 8) = o;
    }
}

// ---------- Conv (implicit GEMM, 32x32x16 MFMA, single-barrier LDS) + bias + stats + full 2x2 pool ----------
// grid (63 row-pairs, 2 w-halves, 32 batch); block 256 = 4 waves.
// wave = (mi = wave&1 -> output row 2rp+mi, ni = wave>>1 -> cout half).
// Wave tile: M=64 px x N=64 couts as 2x2 tiles of 32x32; K = 576 (9 taps x 64 cin).
__global__ __launch_bounds__(256, 4)
void conv_mfma_kernel(const _Float16* __restrict__ xh, const _Float16* __restrict__ Wh,
                      const float* __restrict__ bias, const float* __restrict__ gamma,
                      const float* __restrict__ scale,
                      _Float16* __restrict__ yp, float* __restrict__ stats)
{
    const int tid  = threadIdx.x;
    const int lane = tid & 63;
    const int wave = tid >> 6;
    const int mi   = wave & 1;
    const int ni   = wave >> 1;
    const int cl   = lane & 31;      // m-lane (px) for A, n-lane (cout) for B/D
    const int q    = lane >> 5;      // k-half
    const int rp   = blockIdx.x;     // 0..62
    const int half = blockIdx.y;     // 0..1
    const int b    = blockIdx.z;

    // [4 input rows][66 px][72 (64 cin + pad8)] f16 ; row stride 4752 elems; 38016 B
    __shared__ _Float16 sx[4 * 66 * 72];

    // ---- stage: wave w stages input row 2rp+w, px half*64 .. +65 ----
    {
        const size_t grow = ((size_t)(b * 128 + 2 * rp + wave)) * 8192 + (size_t)half * 64 * 64;
        const int pxl = lane >> 3, cb = lane & 7;
        _Float16* dst = sx + wave * 4752;
        #pragma unroll
        for (int it = 0; it < 8; ++it) {
            const int px = it * 8 + pxl;
            const f16x8 v = *(const f16x8*)(xh + grow + px * 64 + cb * 8);
            *(f16x8*)(dst + px * 72 + cb * 8) = v;
        }
        if (lane < 16) {                       // px 64,65 halo (may over-read 256B past row: xh has slack)
            const int px = 64 + (lane >> 3);
            const f16x8 v = *(const f16x8*)(xh + grow + px * 64 + cb * 8);
            *(f16x8*)(dst + px * 72 + cb * 8) = v;
        }
    }
    __syncthreads();

    f32x16 acc[2][2] = {};

    const _Float16* apbase = sx + cl * 72 + q * 8;             // + (mi+kh)*4752 + kw*72 + mt*2304 + t*16
    const _Float16* bpbase = Wh + (ni * 64 + cl) * 64 + q * 8; // + kk*8192 + nt*2048 + t*16

    #pragma unroll 1
    for (int kh = 0; kh < 3; ++kh) {
        const _Float16* aph = apbase + (mi + kh) * 4752;
        const _Float16* bph = bpbase + kh * 3 * 8192;
        #pragma unroll
        for (int kw = 0; kw < 3; ++kw) {
            const _Float16* ap = aph + kw * 72;
            const _Float16* bp = bph + kw * 8192;
            #pragma unroll
            for (int t = 0; t < 4; ++t) {
                const f16x8 a0 = *(const f16x8*)(ap + t * 16);
                const f16x8 a1 = *(const f16x8*)(ap + 2304 + t * 16);
                const f16x8 b0 = *(const f16x8*)(bp + t * 16);
                const f16x8 b1 = *(const f16x8*)(bp + 2048 + t * 16);
                acc[0][0] = __builtin_amdgcn_mfma_f32_32x32x16_f16(a0, b0, acc[0][0], 0, 0, 0);
                acc[0][1] = __builtin_amdgcn_mfma_f32_32x32x16_f16(a0, b1, acc[0][1], 0, 0, 0);
                acc[1][0] = __builtin_amdgcn_mfma_f32_32x32x16_f16(a1, b0, acc[1][0], 0, 0, 0);
                acc[1][1] = __builtin_amdgcn_mfma_f32_32x32x16_f16(a1, b1, acc[1][1], 0, 0, 0);
            }
        }
    }

    // ---- epilogue: bias, stats, horizontal pool (adjacent regs), vertical pool via LDS exchange ----
    // D layout (32x32): col(cout)=cl, row(px)= (r&3) + 4*q + 8*(r>>2); pairs (r=4ru+2pl, +1).
    float ev[2][2][4][2];   // [nt][mt][ru][pl] horizontal extremum
    float s1[2] = {0.f, 0.f}, s2[2] = {0.f, 0.f};
    bool  useMin[2];
    #pragma unroll
    for (int nt = 0; nt < 2; ++nt) {
        const int co = ni * 64 + nt * 32 + cl;
        const float bv = bias[co];
        useMin[nt] = (gamma[co] * scale[co]) < 0.0f;   // affine slope sign (rstd>0)
        #pragma unroll
        for (int mt = 0; mt < 2; ++mt)
            #pragma unroll
            for (int ru = 0; ru < 4; ++ru)
                #pragma unroll
                for (int pl = 0; pl < 2; ++pl) {
                    const float e0 = acc[mt][nt][ru * 4 + pl * 2 + 0] + bv;
                    const float e1 = acc[mt][nt][ru * 4 + pl * 2 + 1] + bv;
                    // wo = half*64 + mt*32 + (2pl+{0,1} + 4q + 8ru); invalid only wo>=126
                    const bool bad = (half == 1) && (mt == 1) && (q == 1) && (ru == 3) && (pl == 1);
                    if (!bad) { s1[nt] += e0 + e1; s2[nt] += e0 * e0 + e1 * e1; }
                    ev[nt][mt][ru][pl] = useMin[nt] ? fminf(e0, e1) : fmaxf(e0, e1);
                }
    }

    // stats: reduce over the 32 lanes sharing a 16-cout group-half: xor 1,2,4,8,32
    #pragma unroll
    for (int nt = 0; nt < 2; ++nt) {
        float a1 = s1[nt], a2 = s2[nt];
        a1 += __shfl_xor(a1, 1);  a2 += __shfl_xor(a2, 1);
        a1 += __shfl_xor(a1, 2);  a2 += __shfl_xor(a2, 2);
        a1 += __shfl_xor(a1, 4);  a2 += __shfl_xor(a2, 4);
        a1 += __shfl_xor(a1, 8);  a2 += __shfl_xor(a2, 8);
        a1 += __shfl_xor(a1, 32); a2 += __shfl_xor(a2, 32);
        if ((lane & 15) == 0 && lane < 32) {
            const int g = ni * 4 + nt * 2 + (cl >> 4);
            atomicAdd(&stats[((size_t)b * NG + g) * 2 + 0], a1);
            atomicAdd(&stats[((size_t)b * NG + g) * 2 + 1], a2);
        }
    }

    // vertical combine: mi=1 publishes, mi=0 combines + stores yp
    __syncthreads();               // all K-loop LDS reads done; safe to reuse sx
    _Float16* ex = sx;             // [ (ni*2+nt)*32 + pp ][ cl ] f16, 8KB
    if (mi == 1) {
        #pragma unroll
        for (int nt = 0; nt < 2; ++nt)
            #pragma unroll
            for (int mt = 0; mt < 2; ++mt)
                #pragma unroll
                for (int ru = 0; ru < 4; ++ru)
                    #pragma unroll
                    for (int pl = 0; pl < 2; ++pl) {
                        const int pp = mt * 16 + ru * 4 + q * 2 + pl;
                        ex[((ni * 2 + nt) * 32 + pp) * 32 + cl] = (_Float16)ev[nt][mt][ru][pl];
                    }
    }
    __syncthreads();
    if (mi == 0) {
        #pragma unroll
        for (int nt = 0; nt < 2; ++nt) {
            const int co = ni * 64 + nt * 32 + cl;
            _Float16* ypp = yp + ((size_t)(b * COUT + co) * HP + rp) * 64 + half * 32;
            #pragma unroll
            for (int mt = 0; mt < 2; ++mt)
                #pragma unroll
                for (int ru = 0; ru < 4; ++ru) {
                    const int ppb = mt * 16 + ru * 4 + q * 2;
                    const float r0 = (float)ex[((ni * 2 + nt) * 32 + ppb + 0) * 32 + cl];
                    const float r1 = (float)ex[((ni * 2 + nt) * 32 + ppb + 1) * 32 + cl];
                    const float c0 = useMin[nt] ? fminf(ev[nt][mt][ru][0], r0) : fmaxf(ev[nt][mt][ru][0], r0);
                    const float c1 = useMin[nt] ? fminf(ev[nt][mt][ru][1], r1) : fmaxf(ev[nt][mt][ru][1], r1);
                    *(f16x2*)(ypp + ppb) = (f16x2){(_Float16)c0, (_Float16)c1};
                }
        }
    }
}

// ---------- GroupNorm affine + clamp on pre-pooled extrema ----------
__global__ __launch_bounds__(256)
void gn_pool_kernel(const _Float16* __restrict__ yp, const float* __restrict__ stats,
                    const float* __restrict__ gamma, const float* __restrict__ beta,
                    const float* __restrict__ scale, float* __restrict__ out)
{
    const int idx = blockIdx.x * 256 + threadIdx.x;
    if (idx >= B_ * COUT * HP * WP) return;
    const int wp = idx % WP;
    const int hp = (idx / WP) % HP;
    const int c  = (idx / (WP * HP)) % COUT;
    const int b  = idx / (WP * HP * COUT);
    const int g  = c >> 4;

    const float s1 = stats[((size_t)b * NG + g) * 2 + 0];
    const float s2 = stats[((size_t)b * NG + g) * 2 + 1];
    constexpr float inv = 1.0f / (float)((COUT / NG) * HO * WO);
    const float mean = s1 * inv;
    const float var  = fmaf(-mean, mean, s2 * inv);
    const float rstd = rsqrtf(var + EPS);
    const float sc   = scale[c];
    const float a    = rstd * gamma[c] * sc;
    const float bb   = fmaf(-mean, rstd * gamma[c], beta[c]) * sc;

    const float v = (float)yp[((size_t)(b * COUT + c) * HP + hp) * 64 + wp];
    float m = fmaf(v, a, bb);
    m = fminf(fmaxf(m, 0.0f), 1.0f);
    out[idx] = m;
}

extern "C" void kernel_launch(void* const* d_in, const int* in_sizes, int n_in,
                              void* d_out, int out_size, void* d_ws, size_t ws_size,
                              hipStream_t stream)
{
    const float* x     = (const float*)d_in[0];
    const float* W     = (const float*)d_in[1];
    const float* bias  = (const float*)d_in[2];
    const float* scale = (const float*)d_in[3];
    const float* gamma = (const float*)d_in[4];
    const float* beta  = (const float*)d_in[5];

    float*    stats = (float*)d_ws;
    _Float16* Wh    = (_Float16*)((char*)d_ws + 4096);
    _Float16* xh    = (_Float16*)((char*)d_ws + 151552);
    _Float16* yp    = (_Float16*)((char*)d_ws + 67264512);
    float*    out   = (float*)d_out;

    hipMemsetAsync(stats, 0, B_ * NG * 2 * sizeof(float), stream);

    whprep_kernel<<<(9 * COUT * CIN + 255) / 256, 256, 0, stream>>>(W, Wh);
    xprep_kernel<<<dim3(64, B_), 256, 0, stream>>>(x, xh);
    conv_mfma_kernel<<<dim3(63, 2, B_), 256, 0, stream>>>(xh, Wh, bias, gamma, scale, yp, stats);

    const int total = B_ * COUT * HP * WP;
    gn_pool_kernel<<<(total + 255) / 256, 256, 0, stream>>>(yp, stats, gamma, beta, scale, out);
}